// Round 14
// baseline (129.766 us; speedup 1.0000x reference)
//
#include <hip/hip_runtime.h>
#include <hip/hip_bf16.h>

typedef __bf16 bf16;
typedef __attribute__((ext_vector_type(8))) __bf16 bf16x8;
typedef __attribute__((ext_vector_type(4))) __bf16 bf16x4;
typedef __attribute__((ext_vector_type(4))) float f32x4;
typedef __attribute__((ext_vector_type(16))) float f32x16;
typedef __attribute__((ext_vector_type(4))) unsigned int u32x4;
typedef __attribute__((ext_vector_type(2))) unsigned int u32x2;

__device__ __forceinline__ void gload_lds16(const void* g, void* l) {
  __builtin_amdgcn_global_load_lds((const __attribute__((address_space(1))) void*)g,
                                   (__attribute__((address_space(3))) void*)l, 16, 0, 0);
}

// R11 lesson: raw inline-asm v_exp_f32 / v_permlane32_swap lack compiler-managed result-use
// hazard handling -> schedule-dependent corruption (R6/R7/R9, oracle-confirmed R11). Builtins only.
__device__ __forceinline__ float exp2_b(float x) { return __builtin_amdgcn_exp2f(x); }
__device__ __forceinline__ void plswap_b(unsigned& a, unsigned& b) {
  u32x2 r = __builtin_amdgcn_permlane32_swap(a, b, false, false);
  a = r[0]; b = r[1];
}
// cvt_pk: no builtin exists; non-TRANS VALU op, oracle-validated safe in asm.
__device__ __forceinline__ unsigned cvtpk(float lo, float hi) {
  unsigned r;
  asm("v_cvt_pk_bf16_f32 %0, %1, %2" : "=v"(r) : "v"(lo), "v"(hi));
  return r;
}

// ---------------- merged f32->bf16 convert (x,y) + weight transpose-convert ----------------
__global__ __launch_bounds__(256) void cvtw_kernel(
    const float* __restrict__ x, const float* __restrict__ y,
    bf16* __restrict__ xb, bf16* __restrict__ yb,
    const float* __restrict__ W0, const float* __restrict__ W1,
    const float* __restrict__ W2, const float* __restrict__ W3,
    bf16* __restrict__ T0, bf16* __restrict__ T1,
    bf16* __restrict__ T2, bf16* __restrict__ T3) {
  __shared__ float t[32][33];
  const int bid = blockIdx.x, tid = threadIdx.x;
  if (bid < 4096) {
    const int z = bid >> 10, rem = bid & 1023;
    const int bx = rem & 31, by = rem >> 5;
    const float* W; bf16* T;
    switch (z) {
      case 0: W = W0; T = T0; break;
      case 1: W = W1; T = T1; break;
      case 2: W = W2; T = T2; break;
      default: W = W3; T = T3; break;
    }
    const int tx = tid & 31, ty = tid >> 5;
    const int bn = bx * 32, bk = by * 32;
#pragma unroll
    for (int i = 0; i < 32; i += 8)
      t[ty + i][tx] = W[(size_t)(bk + ty + i) * 1024 + bn + tx];
    __syncthreads();
#pragma unroll
    for (int i = 0; i < 32; i += 8)
      T[(size_t)(bn + ty + i) * 1024 + bk + tx] = (bf16)t[tx][ty + i];
  } else {
    const int n4 = 1048576;
    int i = (bid - 4096) * 256 + tid;
    const float4* in = (const float4*)x; bf16x4* out = (bf16x4*)xb;
    if (i >= n4) { in = (const float4*)y; out = (bf16x4*)yb; i -= n4; }
    float4 v = in[i];
    bf16x4 o;
    o[0] = (bf16)v.x; o[1] = (bf16)v.y; o[2] = (bf16)v.z; o[3] = (bf16)v.w;
    out[i] = o;
  }
}

// ---------------- merged Q/K/V projection GEMM, 128x128 tile, 8 waves, double-buffered --------
__global__ __launch_bounds__(512, 6) void gemm_qkv(
    const bf16* __restrict__ xb, const bf16* __restrict__ yb,
    const bf16* __restrict__ Wqt, const bf16* __restrict__ Wkt, const bf16* __restrict__ Wvt,
    const float* __restrict__ bq, const float* __restrict__ bk, const float* __restrict__ bv,
    bf16* __restrict__ Qb, bf16* __restrict__ Kb, bf16* __restrict__ Vtb) {
  constexpr int K = 1024;
  constexpr float QSCALE = (float)(1.4426950408889634 / 45.254833995939045);
  __shared__ bf16 As[2][128 * 32];
  __shared__ bf16 Bs[2][128 * 32];
  const int z = blockIdx.z;
  const bf16* A  = (z == 0) ? xb : yb;
  const bf16* Bt = (z == 0) ? Wqt : (z == 1) ? Wkt : Wvt;
  const float* bias = (z == 0) ? bq : (z == 1) ? bk : bv;

  const int tid = threadIdx.x;
  const int wave = tid >> 6, lane = tid & 63;
  const int g = lane >> 4, r15 = lane & 15;
  const int m0 = blockIdx.x * 128, n0 = blockIdx.y * 128;
  const int wr = wave >> 2, wc = wave & 3;

  f32x4 acc[4][2] = {};

  const int rowA = tid >> 2, chA = tid & 3;

  auto stage = [&](int buf, int k0) {
    gload_lds16(A  + (size_t)(m0 + rowA) * K + k0 + chA * 8, (char*)As[buf] + tid * 16);
    gload_lds16(Bt + (size_t)(n0 + rowA) * K + k0 + chA * 8, (char*)Bs[buf] + tid * 16);
  };

  stage(0, 0);
  __syncthreads();
  int cur = 0;
  for (int t = 0; t < K / 32; ++t) {
    if (t + 1 < K / 32) stage(cur ^ 1, (t + 1) * 32);
    bf16x8 af[4], bfr[2];
#pragma unroll
    for (int mi = 0; mi < 4; ++mi)
      af[mi] = *(const bf16x8*)((const char*)As[cur] + ((wr * 64 + mi * 16 + r15) * 64 + g * 16));
#pragma unroll
    for (int nj = 0; nj < 2; ++nj)
      bfr[nj] = *(const bf16x8*)((const char*)Bs[cur] + ((wc * 32 + nj * 16 + r15) * 64 + g * 16));
#pragma unroll
    for (int mi = 0; mi < 4; ++mi)
#pragma unroll
      for (int nj = 0; nj < 2; ++nj)
        acc[mi][nj] = __builtin_amdgcn_mfma_f32_16x16x32_bf16(af[mi], bfr[nj], acc[mi][nj], 0, 0, 0);
    __syncthreads();
    cur ^= 1;
  }

  const float scl = (z == 0) ? QSCALE : 1.0f;
#pragma unroll
  for (int mi = 0; mi < 4; ++mi) {
#pragma unroll
    for (int nj = 0; nj < 2; ++nj) {
      int row = m0 + wr * 64 + mi * 16 + g * 4;
      int col = n0 + wc * 32 + nj * 16 + r15;
      float bv_ = bias[col];
      if (z < 2) {
        bf16* C = (z == 0) ? Qb : Kb;
#pragma unroll
        for (int r = 0; r < 4; ++r)
          C[(size_t)(row + r) * 1024 + col] = (bf16)((acc[mi][nj][r] + bv_) * scl);
      } else {
        int b = row >> 11, n = row & 2047;
        bf16x4 pkv;
#pragma unroll
        for (int r = 0; r < 4; ++r)
          pkv[r] = (bf16)(acc[mi][nj][r] + bv_);
        *(bf16x4*)(Vtb + ((size_t)b * 1024 + col) * 2048 + n) = pkv;
      }
    }
  }
}

// ---------------- out-projection GEMM, 128x64 tile, 8 waves, bias+ReLU, f32 out ----------------
__global__ __launch_bounds__(512, 4) void gemm_out(
    const bf16* __restrict__ A, const bf16* __restrict__ Bt,
    const float* __restrict__ bias, float* __restrict__ C) {
  constexpr int K = 1024;
  __shared__ bf16 As[2][128 * 32];
  __shared__ bf16 Bs[2][64 * 32];
  const int tid = threadIdx.x;
  const int wave = tid >> 6, lane = tid & 63;
  const int g = lane >> 4, r15 = lane & 15;
  const int m0 = blockIdx.x * 128, n0 = blockIdx.y * 64;
  const int wr = wave >> 1, wc = wave & 1;

  f32x4 acc[2][2] = {};

  const int rowA = tid >> 2, chA = tid & 3;

  auto stage = [&](int buf, int k0) {
    gload_lds16(A + (size_t)(m0 + rowA) * K + k0 + chA * 8, (char*)As[buf] + tid * 16);
    if (tid < 256)
      gload_lds16(Bt + (size_t)(n0 + rowA) * K + k0 + chA * 8, (char*)Bs[buf] + tid * 16);
  };

  stage(0, 0);
  __syncthreads();
  int cur = 0;
  for (int t = 0; t < K / 32; ++t) {
    if (t + 1 < K / 32) stage(cur ^ 1, (t + 1) * 32);
    bf16x8 af[2], bfr[2];
#pragma unroll
    for (int mi = 0; mi < 2; ++mi)
      af[mi] = *(const bf16x8*)((const char*)As[cur] + ((wr * 32 + mi * 16 + r15) * 64 + g * 16));
#pragma unroll
    for (int nj = 0; nj < 2; ++nj)
      bfr[nj] = *(const bf16x8*)((const char*)Bs[cur] + ((wc * 32 + nj * 16 + r15) * 64 + g * 16));
#pragma unroll
    for (int mi = 0; mi < 2; ++mi)
#pragma unroll
      for (int nj = 0; nj < 2; ++nj)
        acc[mi][nj] = __builtin_amdgcn_mfma_f32_16x16x32_bf16(af[mi], bfr[nj], acc[mi][nj], 0, 0, 0);
    __syncthreads();
    cur ^= 1;
  }

#pragma unroll
  for (int mi = 0; mi < 2; ++mi)
#pragma unroll
    for (int nj = 0; nj < 2; ++nj) {
      int row = m0 + wr * 32 + mi * 16 + g * 4;
      int col = n0 + wc * 32 + nj * 16 + r15;
      float bv_ = bias[col];
#pragma unroll
      for (int r = 0; r < 4; ++r)
        C[(size_t)(row + r) * 1024 + col] = fmaxf(acc[mi][nj][r] + bv_, 0.0f);
    }
}

// ---------------- flash attention v7: v6-builtin + T4 counted-vmcnt triple-buffer --------------
// 4 waves (kv-half x q-half), QBLK=64, 1024 blocks XCD-grouped. K/V triple-buffered (48KB,
// 3 blocks/CU); tile t+2 staged at phase start; phase-end barrier = s_waitcnt vmcnt(4)
// lgkmcnt(0) + raw s_barrier + sched_barrier(0) -> t+2's 4 loads/wave stay in flight across
// the barrier (full-phase latency cover) instead of __syncthreads' vmcnt(0) drain.
// Q prescaled by log2e/sqrt(2048). Q,K: [B][2048][1024] bf16. V^T: [B][1024][2048] bf16.
__global__ __launch_bounds__(256, 3) void attn_kernel(
    const bf16* __restrict__ Q, const bf16* __restrict__ Kin,
    const bf16* __restrict__ Vt, bf16* __restrict__ Oa) {
  __shared__ bf16 Ks[3][64 * 64];
  __shared__ bf16 Vs[3][64 * 64];
  const int tid = threadIdx.x;
  const int w = tid >> 6, lane = tid & 63;
  const int q5 = lane & 31, h = lane >> 5;
  const int kh = w & 1, qh = w >> 1;

  // XCD-grouped mapping: each XCD owns 4 bh panels x 32 q-tiles
  int i = blockIdx.y * 32 + blockIdx.x;
  int xcd = i & 7, slot = i >> 3;
  int bh = xcd * 4 + (slot >> 5), qt = slot & 31;
  int b = bh >> 4, hd = bh & 15;

  const bf16* Qg = Q + ((size_t)b * 2048 + qt * 64 + qh * 32) * 1024 + hd * 64;
  const bf16* Kg = Kin + (size_t)b * 2048 * 1024 + hd * 64;
  const bf16* Vg = Vt + ((size_t)b * 1024 + hd * 64) * 2048;

  // Q B-fragments: lane holds Q[q = qh*32+q5][k = 16ks+8h+j]
  bf16x8 qf[4];
#pragma unroll
  for (int ks = 0; ks < 4; ++ks)
    qf[ks] = *(const bf16x8*)(Qg + (size_t)q5 * 1024 + ks * 16 + h * 8);

  f32x16 o[2] = {};  // [j]: j=0 -> own d-block (db=kh), j=1 -> partner (db=1-kh)
  float ls = 0.0f;

  // each wave issues exactly 4 gload_lds per stage call (vmcnt arithmetic relies on this)
  auto stage = [&](int buf, int kv0) {
#pragma unroll
    for (int ii = 0; ii < 2; ++ii) {
      int c = tid + ii * 256;
      int row = c >> 3;
      int sl = (c & 7) ^ (row & 7) ^ ((row >> 3) & 1);  // pre-swizzled global source chunk
      gload_lds16(Kg + (size_t)(kv0 + row) * 1024 + sl * 8, (char*)Ks[buf] + c * 16);
      gload_lds16(Vg + (size_t)row * 2048 + kv0 + sl * 8, (char*)Vs[buf] + c * 16);
    }
  };

  // prologue: stage tiles 0 and 1; wait for tile 0 only (tile 1's 4 loads stay in flight)
  stage(0, 0);
  stage(1, 64);
  asm volatile("s_waitcnt vmcnt(4)" ::: "memory");
  __builtin_amdgcn_s_barrier();
  __builtin_amdgcn_sched_barrier(0);

  const int krow = kh * 32 + q5;
  const int kswz = (krow & 7) ^ ((krow >> 3) & 1);

  // two-deep pipeline state (static names — no runtime-indexed arrays)
  unsigned uA[8], uB[8];
  bf16x8 vA[4], vB[4];

  // phase t: stage(t+2) early | QK(t) | ldV(t)->vout | PV(t-1) | exp/pack(t) |
  //          vmcnt(4) lgkmcnt(0) + s_barrier (t+2 loads cross the barrier)
  auto phase = [&](int t, unsigned (&uin)[8], unsigned (&uout)[8],
                   bf16x8 (&vin)[4], bf16x8 (&vout)[4], bool doPV) {
    int rb = t % 3;
    const bool doStage = (t + 2 <= 31);
    if (doStage) stage((t + 2) % 3, (t + 2) * 64);

    // S^T = K_kh * Q_qh^T : 32kv x 32q
    f32x16 s = {};
    __builtin_amdgcn_s_setprio(1);
#pragma unroll
    for (int ks = 0; ks < 4; ++ks) {
      bf16x8 kf = *(const bf16x8*)((const char*)Ks[rb] + krow * 128 + (((2 * ks + h) ^ kswz) << 4));
      s = __builtin_amdgcn_mfma_f32_32x32x16_bf16(kf, qf[ks], s, 0, 0, 0);
    }

    // V(t) fragments -> registers
#pragma unroll
    for (int j = 0; j < 2; ++j) {
      const int db = kh ^ j;
      const int vrow0 = db * 32 + q5;
      const int vswz = (vrow0 & 7) ^ ((vrow0 >> 3) & 1);
#pragma unroll
      for (int kap = 0; kap < 2; ++kap)
        vout[2 * j + kap] = *(const bf16x8*)((const char*)Vs[rb] + vrow0 * 128 +
                                             (((4 * kh + 2 * kap + h) ^ vswz) << 4));
    }

    // PV(t-1): fully register-fed, fills MFMA pipe while s(t) drains
    if (doPV) {
#pragma unroll
      for (int j = 0; j < 2; ++j)
#pragma unroll
        for (int kap = 0; kap < 2; ++kap) {
          u32x4 uw;
          uw[0] = uin[4 * kap + 0]; uw[1] = uin[4 * kap + 1];
          uw[2] = uin[4 * kap + 2]; uw[3] = uin[4 * kap + 3];
          bf16x8 pa = __builtin_bit_cast(bf16x8, uw);
          o[j] = __builtin_amdgcn_mfma_f32_32x32x16_bf16(pa, vin[2 * j + kap], o[j], 0, 0, 0);
        }
    }
    __builtin_amdgcn_s_setprio(0);

    // P(t) = exp2(S), pack, permlane half-exchange (builtins: hazard-safe)
    float e[16];
#pragma unroll
    for (int jj = 0; jj < 16; ++jj) e[jj] = exp2_b(s[jj]);
    ls += ((((e[0] + e[1]) + (e[2] + e[3])) + ((e[4] + e[5]) + (e[6] + e[7]))) +
           (((e[8] + e[9]) + (e[10] + e[11])) + ((e[12] + e[13]) + (e[14] + e[15]))));
#pragma unroll
    for (int p = 0; p < 8; ++p) uout[p] = cvtpk(e[2 * p], e[2 * p + 1]);
    plswap_b(uout[0], uout[2]); plswap_b(uout[1], uout[3]);
    plswap_b(uout[4], uout[6]); plswap_b(uout[5], uout[7]);

    // counted-vmcnt barrier: force tile-(t+1) loads (oldest) complete; keep t+2's 4 in flight.
    // lgkmcnt(0): all this phase's LDS reads done -> next phase may overwrite buf[(t+2)%3].
    if (doStage) {
      asm volatile("s_waitcnt vmcnt(4) lgkmcnt(0)" ::: "memory");
    } else {
      asm volatile("s_waitcnt vmcnt(0) lgkmcnt(0)" ::: "memory");
    }
    __builtin_amdgcn_s_barrier();
    __builtin_amdgcn_sched_barrier(0);
  };

  // prologue phase: tile 0 (no PV)
  phase(0, uB, uA, vB, vA, false);
  // steady state: tiles 1..30 in pairs
  for (int t = 1; t < 31; t += 2) {
    phase(t, uA, uB, vA, vB, true);
    phase(t + 1, uB, uA, vB, vA, true);
  }
  // tail: tile 31, then final PV(31)
  phase(31, uA, uB, vA, vB, true);
#pragma unroll
  for (int j = 0; j < 2; ++j)
#pragma unroll
    for (int kap = 0; kap < 2; ++kap) {
      u32x4 uw;
      uw[0] = uB[4 * kap + 0]; uw[1] = uB[4 * kap + 1];
      uw[2] = uB[4 * kap + 2]; uw[3] = uB[4 * kap + 3];
      bf16x8 pa = __builtin_bit_cast(bf16x8, uw);
      o[j] = __builtin_amdgcn_mfma_f32_32x32x16_bf16(pa, vB[2 * j + kap], o[j], 0, 0, 0);
    }

  // ls: cross-h reduce -> every lane holds this wave's 32-kv half-sum for q=q5
  ls += __shfl_xor(ls, 32);

  // cross-wave combine via LDS overlay (Ks/Vs dead; phase(31) used vmcnt(0)+lgkmcnt(0))
  float* osh = (float*)Ks;  // [4 waves][64 lanes][16] f32 = 16 KB (fits in 24 KB Ks)
  float* lsf = (float*)Vs;  // [4 waves][32] f32
  *(f32x16*)(osh + ((size_t)(w * 64 + lane)) * 16) = o[1];
  if (h == 0) lsf[w * 32 + q5] = ls;
  __syncthreads();

  const int pw = w ^ 1;  // partner: same q-half, other kv-half
  float lt = ls + lsf[pw * 32 + q5];
  float iv = __builtin_amdgcn_rcpf(lt);
  f32x16 p = *(const f32x16*)(osh + ((size_t)(pw * 64 + lane)) * 16);
#pragma unroll
  for (int g4 = 0; g4 < 4; ++g4)
#pragma unroll
    for (int r = 0; r < 4; ++r) {
      int qr = g4 * 8 + 4 * h + r;
      float il = __shfl(iv, qr);
      size_t row = (size_t)b * 2048 + qt * 64 + qh * 32 + qr;
      Oa[row * 1024 + hd * 64 + kh * 32 + q5] = (bf16)((o[0][g4 * 4 + r] + p[g4 * 4 + r]) * il);
    }
}

extern "C" void kernel_launch(void* const* d_in, const int* in_sizes, int n_in,
                              void* d_out, int out_size, void* d_ws, size_t ws_size,
                              hipStream_t stream) {
  (void)in_sizes; (void)n_in; (void)out_size; (void)ws_size;
  const float* x  = (const float*)d_in[0];
  const float* y  = (const float*)d_in[1];
  const float* Wq = (const float*)d_in[2];
  const float* bq = (const float*)d_in[3];
  const float* Wk = (const float*)d_in[4];
  const float* bk = (const float*)d_in[5];
  const float* Wv = (const float*)d_in[6];
  const float* bv = (const float*)d_in[7];
  const float* Wo = (const float*)d_in[8];
  const float* bo = (const float*)d_in[9];

  char* ws = (char*)d_ws;
  bf16* xb  = (bf16*)(ws + 0);
  bf16* yb  = (bf16*)(ws + 8388608);
  bf16* Qb  = (bf16*)(ws + 16777216);
  bf16* Kb  = (bf16*)(ws + 25165824);
  bf16* Vtb = (bf16*)(ws + 33554432);
  bf16* Oab = (bf16*)(ws + 41943040);
  bf16* Wqt = (bf16*)(ws + 50331648);
  bf16* Wkt = (bf16*)(ws + 52428800);
  bf16* Wvt = (bf16*)(ws + 54525952);
  bf16* Wot = (bf16*)(ws + 56623104);

  cvtw_kernel<<<12288, 256, 0, stream>>>(x, y, xb, yb, Wq, Wk, Wv, Wo, Wqt, Wkt, Wvt, Wot);
  gemm_qkv<<<dim3(32, 8, 3), 512, 0, stream>>>(xb, yb, Wqt, Wkt, Wvt, bq, bk, bv, Qb, Kb, Vtb);
  attn_kernel<<<dim3(32, 32), dim3(256), 0, stream>>>(Qb, Kb, Vtb, Oab);
  gemm_out<<<dim3(32, 16), 512, 0, stream>>>(Oab, Wot, bo, (float*)d_out);
}

// Round 15
// 128.993 us; speedup vs baseline: 1.0060x; 1.0060x over previous
//
#include <hip/hip_runtime.h>
#include <hip/hip_bf16.h>

typedef __bf16 bf16;
typedef __attribute__((ext_vector_type(8))) __bf16 bf16x8;
typedef __attribute__((ext_vector_type(4))) __bf16 bf16x4;
typedef __attribute__((ext_vector_type(4))) float f32x4;
typedef __attribute__((ext_vector_type(16))) float f32x16;
typedef __attribute__((ext_vector_type(4))) unsigned int u32x4;
typedef __attribute__((ext_vector_type(2))) unsigned int u32x2;

__device__ __forceinline__ void gload_lds16(const void* g, void* l) {
  __builtin_amdgcn_global_load_lds((const __attribute__((address_space(1))) void*)g,
                                   (__attribute__((address_space(3))) void*)l, 16, 0, 0);
}

// R11 lesson: raw inline-asm v_exp_f32 / v_permlane32_swap lack compiler-managed result-use
// hazard handling -> schedule-dependent corruption (R6/R7/R9, oracle-confirmed R11). Builtins only.
__device__ __forceinline__ float exp2_b(float x) { return __builtin_amdgcn_exp2f(x); }
__device__ __forceinline__ void plswap_b(unsigned& a, unsigned& b) {
  u32x2 r = __builtin_amdgcn_permlane32_swap(a, b, false, false);
  a = r[0]; b = r[1];
}
// cvt_pk: no builtin exists; non-TRANS VALU op, oracle-validated safe in asm.
__device__ __forceinline__ unsigned cvtpk(float lo, float hi) {
  unsigned r;
  asm("v_cvt_pk_bf16_f32 %0, %1, %2" : "=v"(r) : "v"(lo), "v"(hi));
  return r;
}

// ---------------- merged f32->bf16 convert (x,y) + weight transpose-convert ----------------
__global__ __launch_bounds__(256) void cvtw_kernel(
    const float* __restrict__ x, const float* __restrict__ y,
    bf16* __restrict__ xb, bf16* __restrict__ yb,
    const float* __restrict__ W0, const float* __restrict__ W1,
    const float* __restrict__ W2, const float* __restrict__ W3,
    bf16* __restrict__ T0, bf16* __restrict__ T1,
    bf16* __restrict__ T2, bf16* __restrict__ T3) {
  __shared__ float t[32][33];
  const int bid = blockIdx.x, tid = threadIdx.x;
  if (bid < 4096) {
    const int z = bid >> 10, rem = bid & 1023;
    const int bx = rem & 31, by = rem >> 5;
    const float* W; bf16* T;
    switch (z) {
      case 0: W = W0; T = T0; break;
      case 1: W = W1; T = T1; break;
      case 2: W = W2; T = T2; break;
      default: W = W3; T = T3; break;
    }
    const int tx = tid & 31, ty = tid >> 5;
    const int bn = bx * 32, bk = by * 32;
#pragma unroll
    for (int i = 0; i < 32; i += 8)
      t[ty + i][tx] = W[(size_t)(bk + ty + i) * 1024 + bn + tx];
    __syncthreads();
#pragma unroll
    for (int i = 0; i < 32; i += 8)
      T[(size_t)(bn + ty + i) * 1024 + bk + tx] = (bf16)t[tx][ty + i];
  } else {
    const int n4 = 1048576;
    int i = (bid - 4096) * 256 + tid;
    const float4* in = (const float4*)x; bf16x4* out = (bf16x4*)xb;
    if (i >= n4) { in = (const float4*)y; out = (bf16x4*)yb; i -= n4; }
    float4 v = in[i];
    bf16x4 o;
    o[0] = (bf16)v.x; o[1] = (bf16)v.y; o[2] = (bf16)v.z; o[3] = (bf16)v.w;
    out[i] = o;
  }
}

// ---------------- merged Q/K/V projection GEMM, 128x128 tile, 8 waves, double-buffered --------
__global__ __launch_bounds__(512, 6) void gemm_qkv(
    const bf16* __restrict__ xb, const bf16* __restrict__ yb,
    const bf16* __restrict__ Wqt, const bf16* __restrict__ Wkt, const bf16* __restrict__ Wvt,
    const float* __restrict__ bq, const float* __restrict__ bk, const float* __restrict__ bv,
    bf16* __restrict__ Qb, bf16* __restrict__ Kb, bf16* __restrict__ Vtb) {
  constexpr int K = 1024;
  constexpr float QSCALE = (float)(1.4426950408889634 / 45.254833995939045);
  __shared__ bf16 As[2][128 * 32];
  __shared__ bf16 Bs[2][128 * 32];
  const int z = blockIdx.z;
  const bf16* A  = (z == 0) ? xb : yb;
  const bf16* Bt = (z == 0) ? Wqt : (z == 1) ? Wkt : Wvt;
  const float* bias = (z == 0) ? bq : (z == 1) ? bk : bv;

  const int tid = threadIdx.x;
  const int wave = tid >> 6, lane = tid & 63;
  const int g = lane >> 4, r15 = lane & 15;
  const int m0 = blockIdx.x * 128, n0 = blockIdx.y * 128;
  const int wr = wave >> 2, wc = wave & 3;

  f32x4 acc[4][2] = {};

  const int rowA = tid >> 2, chA = tid & 3;

  auto stage = [&](int buf, int k0) {
    gload_lds16(A  + (size_t)(m0 + rowA) * K + k0 + chA * 8, (char*)As[buf] + tid * 16);
    gload_lds16(Bt + (size_t)(n0 + rowA) * K + k0 + chA * 8, (char*)Bs[buf] + tid * 16);
  };

  stage(0, 0);
  __syncthreads();
  int cur = 0;
  for (int t = 0; t < K / 32; ++t) {
    if (t + 1 < K / 32) stage(cur ^ 1, (t + 1) * 32);
    bf16x8 af[4], bfr[2];
#pragma unroll
    for (int mi = 0; mi < 4; ++mi)
      af[mi] = *(const bf16x8*)((const char*)As[cur] + ((wr * 64 + mi * 16 + r15) * 64 + g * 16));
#pragma unroll
    for (int nj = 0; nj < 2; ++nj)
      bfr[nj] = *(const bf16x8*)((const char*)Bs[cur] + ((wc * 32 + nj * 16 + r15) * 64 + g * 16));
#pragma unroll
    for (int mi = 0; mi < 4; ++mi)
#pragma unroll
      for (int nj = 0; nj < 2; ++nj)
        acc[mi][nj] = __builtin_amdgcn_mfma_f32_16x16x32_bf16(af[mi], bfr[nj], acc[mi][nj], 0, 0, 0);
    __syncthreads();
    cur ^= 1;
  }

  const float scl = (z == 0) ? QSCALE : 1.0f;
#pragma unroll
  for (int mi = 0; mi < 4; ++mi) {
#pragma unroll
    for (int nj = 0; nj < 2; ++nj) {
      int row = m0 + wr * 64 + mi * 16 + g * 4;
      int col = n0 + wc * 32 + nj * 16 + r15;
      float bv_ = bias[col];
      if (z < 2) {
        bf16* C = (z == 0) ? Qb : Kb;
#pragma unroll
        for (int r = 0; r < 4; ++r)
          C[(size_t)(row + r) * 1024 + col] = (bf16)((acc[mi][nj][r] + bv_) * scl);
      } else {
        int b = row >> 11, n = row & 2047;
        bf16x4 pkv;
#pragma unroll
        for (int r = 0; r < 4; ++r)
          pkv[r] = (bf16)(acc[mi][nj][r] + bv_);
        *(bf16x4*)(Vtb + ((size_t)b * 1024 + col) * 2048 + n) = pkv;
      }
    }
  }
}

// ---------------- out-projection GEMM, 128x64 tile, 8 waves, bias+ReLU, f32 out ----------------
__global__ __launch_bounds__(512, 4) void gemm_out(
    const bf16* __restrict__ A, const bf16* __restrict__ Bt,
    const float* __restrict__ bias, float* __restrict__ C) {
  constexpr int K = 1024;
  __shared__ bf16 As[2][128 * 32];
  __shared__ bf16 Bs[2][64 * 32];
  const int tid = threadIdx.x;
  const int wave = tid >> 6, lane = tid & 63;
  const int g = lane >> 4, r15 = lane & 15;
  const int m0 = blockIdx.x * 128, n0 = blockIdx.y * 64;
  const int wr = wave >> 1, wc = wave & 1;

  f32x4 acc[2][2] = {};

  const int rowA = tid >> 2, chA = tid & 3;

  auto stage = [&](int buf, int k0) {
    gload_lds16(A + (size_t)(m0 + rowA) * K + k0 + chA * 8, (char*)As[buf] + tid * 16);
    if (tid < 256)
      gload_lds16(Bt + (size_t)(n0 + rowA) * K + k0 + chA * 8, (char*)Bs[buf] + tid * 16);
  };

  stage(0, 0);
  __syncthreads();
  int cur = 0;
  for (int t = 0; t < K / 32; ++t) {
    if (t + 1 < K / 32) stage(cur ^ 1, (t + 1) * 32);
    bf16x8 af[2], bfr[2];
#pragma unroll
    for (int mi = 0; mi < 2; ++mi)
      af[mi] = *(const bf16x8*)((const char*)As[cur] + ((wr * 32 + mi * 16 + r15) * 64 + g * 16));
#pragma unroll
    for (int nj = 0; nj < 2; ++nj)
      bfr[nj] = *(const bf16x8*)((const char*)Bs[cur] + ((wc * 32 + nj * 16 + r15) * 64 + g * 16));
#pragma unroll
    for (int mi = 0; mi < 2; ++mi)
#pragma unroll
      for (int nj = 0; nj < 2; ++nj)
        acc[mi][nj] = __builtin_amdgcn_mfma_f32_16x16x32_bf16(af[mi], bfr[nj], acc[mi][nj], 0, 0, 0);
    __syncthreads();
    cur ^= 1;
  }

#pragma unroll
  for (int mi = 0; mi < 2; ++mi)
#pragma unroll
    for (int nj = 0; nj < 2; ++nj) {
      int row = m0 + wr * 32 + mi * 16 + g * 4;
      int col = n0 + wc * 32 + nj * 16 + r15;
      float bv_ = bias[col];
#pragma unroll
      for (int r = 0; r < 4; ++r)
        C[(size_t)(row + r) * 1024 + col] = fmaxf(acc[mi][nj][r] + bv_, 0.0f);
    }
}

// ---------------- flash attention v8: fused 2-tile phases, 8 waves, QBLK=128 ------------------
// R13's per-tile schedule verbatim (same skewed PV(t-1), same u/v alternation, same swizzles),
// but 512-thread blocks (kv-half x q-quarter), QBLK=128, and TWO 64-kv tiles per barrier:
// 17 barriers instead of 33 at the same 16 waves/CU (512 blocks = 2/CU x 8 waves, 1 round).
// LDS: K/V 4x8KB each = 64KB dbuf. Q prescaled by log2e/sqrt(2048).
// Q,K: [B][2048][1024] bf16. V^T: [B][1024][2048] bf16.
__global__ __launch_bounds__(512, 4) void attn_kernel(
    const bf16* __restrict__ Q, const bf16* __restrict__ Kin,
    const bf16* __restrict__ Vt, bf16* __restrict__ Oa) {
  __shared__ bf16 Ks[4][64 * 64];  // [buf*2+parity]
  __shared__ bf16 Vs[4][64 * 64];
  const int tid = threadIdx.x;
  const int w = tid >> 6, lane = tid & 63;
  const int q5 = lane & 31, h = lane >> 5;
  const int kh = w & 1, qh = w >> 1;  // kv-half, q-quarter

  // XCD-grouped mapping: 512 blocks = 8 XCD x (4 bh panels x 16 q-tiles)
  int i = blockIdx.y * 32 + blockIdx.x;
  int xcd = i & 7, slot = i >> 3;
  int bh = xcd * 4 + (slot >> 4), qt = slot & 15;
  int b = bh >> 4, hd = bh & 15;

  const bf16* Qg = Q + ((size_t)b * 2048 + qt * 128 + qh * 32) * 1024 + hd * 64;
  const bf16* Kg = Kin + (size_t)b * 2048 * 1024 + hd * 64;
  const bf16* Vg = Vt + ((size_t)b * 1024 + hd * 64) * 2048;

  // Q B-fragments: lane holds Q[q = qh*32+q5][k = 16ks+8h+j]
  bf16x8 qf[4];
#pragma unroll
  for (int ks = 0; ks < 4; ++ks)
    qf[ks] = *(const bf16x8*)(Qg + (size_t)q5 * 1024 + ks * 16 + h * 8);

  f32x16 o[2] = {};  // [j]: j=0 -> own d-block (db=kh), j=1 -> partner (db=1-kh)
  float ls = 0.0f;

  // stage both 64-kv tiles of a 128-kv super-tile (512 threads: 1 K + 1 V gload per parity)
  auto stage = [&](int buf, int kv0) {
#pragma unroll
    for (int p = 0; p < 2; ++p) {
      int c = tid;
      int row = c >> 3;
      int sl = (c & 7) ^ (row & 7) ^ ((row >> 3) & 1);  // pre-swizzled global source chunk
      gload_lds16(Kg + (size_t)(kv0 + p * 64 + row) * 1024 + sl * 8, (char*)Ks[buf * 2 + p] + c * 16);
      gload_lds16(Vg + (size_t)row * 2048 + kv0 + p * 64 + sl * 8, (char*)Vs[buf * 2 + p] + c * 16);
    }
  };

  stage(0, 0);
  __syncthreads();
  int cur = 0;

  const int krow = kh * 32 + q5;
  const int kswz = (krow & 7) ^ ((krow >> 3) & 1);

  // two-deep pipeline state (static names — no runtime-indexed arrays)
  unsigned uA[8], uB[8];
  bf16x8 vA[4], vB[4];

  // one 64-kv sub-tile: QK(t) + ldV(t)->vout + PV(t-1) from uin/vin + exp/pack(t)->uout
  auto subtile = [&](int slot4, unsigned (&uin)[8], unsigned (&uout)[8],
                     bf16x8 (&vin)[4], bf16x8 (&vout)[4], bool doPV) {
    // S^T = K_kh * Q_qh^T : 32kv x 32q
    f32x16 s = {};
    __builtin_amdgcn_s_setprio(1);
#pragma unroll
    for (int ks = 0; ks < 4; ++ks) {
      bf16x8 kf = *(const bf16x8*)((const char*)Ks[slot4] + krow * 128 + (((2 * ks + h) ^ kswz) << 4));
      s = __builtin_amdgcn_mfma_f32_32x32x16_bf16(kf, qf[ks], s, 0, 0, 0);
    }

    // V fragments -> registers
#pragma unroll
    for (int j = 0; j < 2; ++j) {
      const int db = kh ^ j;
      const int vrow0 = db * 32 + q5;
      const int vswz = (vrow0 & 7) ^ ((vrow0 >> 3) & 1);
#pragma unroll
      for (int kap = 0; kap < 2; ++kap)
        vout[2 * j + kap] = *(const bf16x8*)((const char*)Vs[slot4] + vrow0 * 128 +
                                             (((4 * kh + 2 * kap + h) ^ vswz) << 4));
    }

    // PV(prev): fully register-fed, fills MFMA pipe while s drains
    if (doPV) {
#pragma unroll
      for (int j = 0; j < 2; ++j)
#pragma unroll
        for (int kap = 0; kap < 2; ++kap) {
          u32x4 uw;
          uw[0] = uin[4 * kap + 0]; uw[1] = uin[4 * kap + 1];
          uw[2] = uin[4 * kap + 2]; uw[3] = uin[4 * kap + 3];
          bf16x8 pa = __builtin_bit_cast(bf16x8, uw);
          o[j] = __builtin_amdgcn_mfma_f32_32x32x16_bf16(pa, vin[2 * j + kap], o[j], 0, 0, 0);
        }
    }
    __builtin_amdgcn_s_setprio(0);

    // P = exp2(S), pack, permlane half-exchange (builtins: hazard-safe)
    float e[16];
#pragma unroll
    for (int jj = 0; jj < 16; ++jj) e[jj] = exp2_b(s[jj]);
    ls += ((((e[0] + e[1]) + (e[2] + e[3])) + ((e[4] + e[5]) + (e[6] + e[7]))) +
           (((e[8] + e[9]) + (e[10] + e[11])) + ((e[12] + e[13]) + (e[14] + e[15]))));
#pragma unroll
    for (int p = 0; p < 8; ++p) uout[p] = cvtpk(e[2 * p], e[2 * p + 1]);
    plswap_b(uout[0], uout[2]); plswap_b(uout[1], uout[3]);
    plswap_b(uout[4], uout[6]); plswap_b(uout[5], uout[7]);
  };

  // 16 fused phases, each covering kv tiles (2k, 2k+1); one barrier per phase
  for (int k = 0; k < 16; ++k) {
    if (k < 15) stage(cur ^ 1, (k + 1) * 128);
    subtile(cur * 2 + 0, uB, uA, vB, vA, k > 0);  // tile 2k:   PV(2k-1)
    subtile(cur * 2 + 1, uA, uB, vA, vB, true);   // tile 2k+1: PV(2k)
    __syncthreads();
    cur ^= 1;
  }
  // final PV(31) from uB/vB (last subtile's outputs)
#pragma unroll
  for (int j = 0; j < 2; ++j)
#pragma unroll
    for (int kap = 0; kap < 2; ++kap) {
      u32x4 uw;
      uw[0] = uB[4 * kap + 0]; uw[1] = uB[4 * kap + 1];
      uw[2] = uB[4 * kap + 2]; uw[3] = uB[4 * kap + 3];
      bf16x8 pa = __builtin_bit_cast(bf16x8, uw);
      o[j] = __builtin_amdgcn_mfma_f32_32x32x16_bf16(pa, vB[2 * j + kap], o[j], 0, 0, 0);
    }

  // ls: cross-h reduce -> every lane holds this wave's 32-kv half-sum for q=q5
  ls += __shfl_xor(ls, 32);

  // cross-wave combine via LDS overlay (Ks/Vs dead after last phase's barrier)
  float* osh = (float*)Ks;  // [8 waves][64 lanes][16] f32 = 32 KB (Ks is 32 KB)
  float* lsf = (float*)Vs;  // [8 waves][32] f32
  *(f32x16*)(osh + ((size_t)(w * 64 + lane)) * 16) = o[1];
  if (h == 0) lsf[w * 32 + q5] = ls;
  __syncthreads();

  const int pw = w ^ 1;  // partner: same q-quarter, other kv-half
  float lt = ls + lsf[pw * 32 + q5];
  float iv = __builtin_amdgcn_rcpf(lt);
  f32x16 p = *(const f32x16*)(osh + ((size_t)(pw * 64 + lane)) * 16);
#pragma unroll
  for (int g4 = 0; g4 < 4; ++g4)
#pragma unroll
    for (int r = 0; r < 4; ++r) {
      int qr = g4 * 8 + 4 * h + r;
      float il = __shfl(iv, qr);
      size_t row = (size_t)b * 2048 + qt * 128 + qh * 32 + qr;
      Oa[row * 1024 + hd * 64 + kh * 32 + q5] = (bf16)((o[0][g4 * 4 + r] + p[g4 * 4 + r]) * il);
    }
}

extern "C" void kernel_launch(void* const* d_in, const int* in_sizes, int n_in,
                              void* d_out, int out_size, void* d_ws, size_t ws_size,
                              hipStream_t stream) {
  (void)in_sizes; (void)n_in; (void)out_size; (void)ws_size;
  const float* x  = (const float*)d_in[0];
  const float* y  = (const float*)d_in[1];
  const float* Wq = (const float*)d_in[2];
  const float* bq = (const float*)d_in[3];
  const float* Wk = (const float*)d_in[4];
  const float* bk = (const float*)d_in[5];
  const float* Wv = (const float*)d_in[6];
  const float* bv = (const float*)d_in[7];
  const float* Wo = (const float*)d_in[8];
  const float* bo = (const float*)d_in[9];

  char* ws = (char*)d_ws;
  bf16* xb  = (bf16*)(ws + 0);
  bf16* yb  = (bf16*)(ws + 8388608);
  bf16* Qb  = (bf16*)(ws + 16777216);
  bf16* Kb  = (bf16*)(ws + 25165824);
  bf16* Vtb = (bf16*)(ws + 33554432);
  bf16* Oab = (bf16*)(ws + 41943040);
  bf16* Wqt = (bf16*)(ws + 50331648);
  bf16* Wkt = (bf16*)(ws + 52428800);
  bf16* Wvt = (bf16*)(ws + 54525952);
  bf16* Wot = (bf16*)(ws + 56623104);

  cvtw_kernel<<<12288, 256, 0, stream>>>(x, y, xb, yb, Wq, Wk, Wv, Wo, Wqt, Wkt, Wvt, Wot);
  gemm_qkv<<<dim3(32, 8, 3), 512, 0, stream>>>(xb, yb, Wqt, Wkt, Wvt, bq, bk, bv, Qb, Kb, Vtb);
  attn_kernel<<<dim3(32, 16), dim3(512), 0, stream>>>(Qb, Kb, Vtb, Oab);
  gemm_out<<<dim3(32, 16), 512, 0, stream>>>(Oab, Wot, bo, (float*)d_out);
}

// Round 16
// 119.162 us; speedup vs baseline: 1.0890x; 1.0825x over previous
//
#include <hip/hip_runtime.h>
#include <hip/hip_bf16.h>

typedef __bf16 bf16;
typedef __attribute__((ext_vector_type(8))) __bf16 bf16x8;
typedef __attribute__((ext_vector_type(4))) __bf16 bf16x4;
typedef __attribute__((ext_vector_type(4))) float f32x4;
typedef __attribute__((ext_vector_type(16))) float f32x16;
typedef __attribute__((ext_vector_type(4))) unsigned int u32x4;
typedef __attribute__((ext_vector_type(2))) unsigned int u32x2;

__device__ __forceinline__ void gload_lds16(const void* g, void* l) {
  __builtin_amdgcn_global_load_lds((const __attribute__((address_space(1))) void*)g,
                                   (__attribute__((address_space(3))) void*)l, 16, 0, 0);
}

// R11 lesson: raw inline-asm v_exp_f32 / v_permlane32_swap lack compiler-managed result-use
// hazard handling -> schedule-dependent corruption (R6/R7/R9, oracle-confirmed R11). Builtins only.
__device__ __forceinline__ float exp2_b(float x) { return __builtin_amdgcn_exp2f(x); }
__device__ __forceinline__ void plswap_b(unsigned& a, unsigned& b) {
  u32x2 r = __builtin_amdgcn_permlane32_swap(a, b, false, false);
  a = r[0]; b = r[1];
}
// cvt_pk: no builtin exists; non-TRANS VALU op, oracle-validated safe in asm.
__device__ __forceinline__ unsigned cvtpk(float lo, float hi) {
  unsigned r;
  asm("v_cvt_pk_bf16_f32 %0, %1, %2" : "=v"(r) : "v"(lo), "v"(hi));
  return r;
}

// ---------------- merged f32->bf16 convert (x,y) + weight transpose-convert ----------------
__global__ __launch_bounds__(256) void cvtw_kernel(
    const float* __restrict__ x, const float* __restrict__ y,
    bf16* __restrict__ xb, bf16* __restrict__ yb,
    const float* __restrict__ W0, const float* __restrict__ W1,
    const float* __restrict__ W2, const float* __restrict__ W3,
    bf16* __restrict__ T0, bf16* __restrict__ T1,
    bf16* __restrict__ T2, bf16* __restrict__ T3) {
  __shared__ float t[32][33];
  const int bid = blockIdx.x, tid = threadIdx.x;
  if (bid < 4096) {
    const int z = bid >> 10, rem = bid & 1023;
    const int bx = rem & 31, by = rem >> 5;
    const float* W; bf16* T;
    switch (z) {
      case 0: W = W0; T = T0; break;
      case 1: W = W1; T = T1; break;
      case 2: W = W2; T = T2; break;
      default: W = W3; T = T3; break;
    }
    const int tx = tid & 31, ty = tid >> 5;
    const int bn = bx * 32, bk = by * 32;
#pragma unroll
    for (int i = 0; i < 32; i += 8)
      t[ty + i][tx] = W[(size_t)(bk + ty + i) * 1024 + bn + tx];
    __syncthreads();
#pragma unroll
    for (int i = 0; i < 32; i += 8)
      T[(size_t)(bn + ty + i) * 1024 + bk + tx] = (bf16)t[tx][ty + i];
  } else {
    const int n4 = 1048576;
    int i = (bid - 4096) * 256 + tid;
    const float4* in = (const float4*)x; bf16x4* out = (bf16x4*)xb;
    if (i >= n4) { in = (const float4*)y; out = (bf16x4*)yb; i -= n4; }
    float4 v = in[i];
    bf16x4 o;
    o[0] = (bf16)v.x; o[1] = (bf16)v.y; o[2] = (bf16)v.z; o[3] = (bf16)v.w;
    out[i] = o;
  }
}

// ---------------- merged Q/K/V projection GEMM, 128x128 tile, 8 waves, double-buffered --------
__global__ __launch_bounds__(512, 6) void gemm_qkv(
    const bf16* __restrict__ xb, const bf16* __restrict__ yb,
    const bf16* __restrict__ Wqt, const bf16* __restrict__ Wkt, const bf16* __restrict__ Wvt,
    const float* __restrict__ bq, const float* __restrict__ bk, const float* __restrict__ bv,
    bf16* __restrict__ Qb, bf16* __restrict__ Kb, bf16* __restrict__ Vtb) {
  constexpr int K = 1024;
  constexpr float QSCALE = (float)(1.4426950408889634 / 45.254833995939045);
  __shared__ bf16 As[2][128 * 32];
  __shared__ bf16 Bs[2][128 * 32];
  const int z = blockIdx.z;
  const bf16* A  = (z == 0) ? xb : yb;
  const bf16* Bt = (z == 0) ? Wqt : (z == 1) ? Wkt : Wvt;
  const float* bias = (z == 0) ? bq : (z == 1) ? bk : bv;

  const int tid = threadIdx.x;
  const int wave = tid >> 6, lane = tid & 63;
  const int g = lane >> 4, r15 = lane & 15;
  const int m0 = blockIdx.x * 128, n0 = blockIdx.y * 128;
  const int wr = wave >> 2, wc = wave & 3;

  f32x4 acc[4][2] = {};

  const int rowA = tid >> 2, chA = tid & 3;

  auto stage = [&](int buf, int k0) {
    gload_lds16(A  + (size_t)(m0 + rowA) * K + k0 + chA * 8, (char*)As[buf] + tid * 16);
    gload_lds16(Bt + (size_t)(n0 + rowA) * K + k0 + chA * 8, (char*)Bs[buf] + tid * 16);
  };

  stage(0, 0);
  __syncthreads();
  int cur = 0;
  for (int t = 0; t < K / 32; ++t) {
    if (t + 1 < K / 32) stage(cur ^ 1, (t + 1) * 32);
    bf16x8 af[4], bfr[2];
#pragma unroll
    for (int mi = 0; mi < 4; ++mi)
      af[mi] = *(const bf16x8*)((const char*)As[cur] + ((wr * 64 + mi * 16 + r15) * 64 + g * 16));
#pragma unroll
    for (int nj = 0; nj < 2; ++nj)
      bfr[nj] = *(const bf16x8*)((const char*)Bs[cur] + ((wc * 32 + nj * 16 + r15) * 64 + g * 16));
#pragma unroll
    for (int mi = 0; mi < 4; ++mi)
#pragma unroll
      for (int nj = 0; nj < 2; ++nj)
        acc[mi][nj] = __builtin_amdgcn_mfma_f32_16x16x32_bf16(af[mi], bfr[nj], acc[mi][nj], 0, 0, 0);
    __syncthreads();
    cur ^= 1;
  }

  const float scl = (z == 0) ? QSCALE : 1.0f;
#pragma unroll
  for (int mi = 0; mi < 4; ++mi) {
#pragma unroll
    for (int nj = 0; nj < 2; ++nj) {
      int row = m0 + wr * 64 + mi * 16 + g * 4;
      int col = n0 + wc * 32 + nj * 16 + r15;
      float bv_ = bias[col];
      if (z < 2) {
        bf16* C = (z == 0) ? Qb : Kb;
#pragma unroll
        for (int r = 0; r < 4; ++r)
          C[(size_t)(row + r) * 1024 + col] = (bf16)((acc[mi][nj][r] + bv_) * scl);
      } else {
        int b = row >> 11, n = row & 2047;
        bf16x4 pkv;
#pragma unroll
        for (int r = 0; r < 4; ++r)
          pkv[r] = (bf16)(acc[mi][nj][r] + bv_);
        *(bf16x4*)(Vtb + ((size_t)b * 1024 + col) * 2048 + n) = pkv;
      }
    }
  }
}

// ---------------- out-projection GEMM, 128x64 tile, 8 waves, bias+ReLU, f32 out ----------------
__global__ __launch_bounds__(512, 4) void gemm_out(
    const bf16* __restrict__ A, const bf16* __restrict__ Bt,
    const float* __restrict__ bias, float* __restrict__ C) {
  constexpr int K = 1024;
  __shared__ bf16 As[2][128 * 32];
  __shared__ bf16 Bs[2][64 * 32];
  const int tid = threadIdx.x;
  const int wave = tid >> 6, lane = tid & 63;
  const int g = lane >> 4, r15 = lane & 15;
  const int m0 = blockIdx.x * 128, n0 = blockIdx.y * 64;
  const int wr = wave >> 1, wc = wave & 1;

  f32x4 acc[2][2] = {};

  const int rowA = tid >> 2, chA = tid & 3;

  auto stage = [&](int buf, int k0) {
    gload_lds16(A + (size_t)(m0 + rowA) * K + k0 + chA * 8, (char*)As[buf] + tid * 16);
    if (tid < 256)
      gload_lds16(Bt + (size_t)(n0 + rowA) * K + k0 + chA * 8, (char*)Bs[buf] + tid * 16);
  };

  stage(0, 0);
  __syncthreads();
  int cur = 0;
  for (int t = 0; t < K / 32; ++t) {
    if (t + 1 < K / 32) stage(cur ^ 1, (t + 1) * 32);
    bf16x8 af[2], bfr[2];
#pragma unroll
    for (int mi = 0; mi < 2; ++mi)
      af[mi] = *(const bf16x8*)((const char*)As[cur] + ((wr * 32 + mi * 16 + r15) * 64 + g * 16));
#pragma unroll
    for (int nj = 0; nj < 2; ++nj)
      bfr[nj] = *(const bf16x8*)((const char*)Bs[cur] + ((wc * 32 + nj * 16 + r15) * 64 + g * 16));
#pragma unroll
    for (int mi = 0; mi < 2; ++mi)
#pragma unroll
      for (int nj = 0; nj < 2; ++nj)
        acc[mi][nj] = __builtin_amdgcn_mfma_f32_16x16x32_bf16(af[mi], bfr[nj], acc[mi][nj], 0, 0, 0);
    __syncthreads();
    cur ^= 1;
  }

#pragma unroll
  for (int mi = 0; mi < 2; ++mi)
#pragma unroll
    for (int nj = 0; nj < 2; ++nj) {
      int row = m0 + wr * 32 + mi * 16 + g * 4;
      int col = n0 + wc * 32 + nj * 16 + r15;
      float bv_ = bias[col];
#pragma unroll
      for (int r = 0; r < 4; ++r)
        C[(size_t)(row + r) * 1024 + col] = fmaxf(acc[mi][nj][r] + bv_, 0.0f);
    }
}

// ---------------- flash attention v9: R15 fused 2-tile phases, DE-SPILLED ---------------------
// Identical to R15 except __launch_bounds__(512, 2): empirically VGPR cap = 256/arg, so the
// previous (512,4) forced 64 VGPRs vs ~110 live state -> ~50 spilled regs -> 60MB scratch
// writes (R15 WRITE_SIZE) and the 70us wall. Cap 128 fits the live state; LDS 64KB still
// bounds residency at 2 blocks/CU = 16 waves/CU = 4 waves/SIMD (unchanged).
__global__ __launch_bounds__(512, 2) void attn_kernel(
    const bf16* __restrict__ Q, const bf16* __restrict__ Kin,
    const bf16* __restrict__ Vt, bf16* __restrict__ Oa) {
  __shared__ bf16 Ks[4][64 * 64];  // [buf*2+parity]
  __shared__ bf16 Vs[4][64 * 64];
  const int tid = threadIdx.x;
  const int w = tid >> 6, lane = tid & 63;
  const int q5 = lane & 31, h = lane >> 5;
  const int kh = w & 1, qh = w >> 1;  // kv-half, q-quarter

  // XCD-grouped mapping: 512 blocks = 8 XCD x (4 bh panels x 16 q-tiles)
  int i = blockIdx.y * 32 + blockIdx.x;
  int xcd = i & 7, slot = i >> 3;
  int bh = xcd * 4 + (slot >> 4), qt = slot & 15;
  int b = bh >> 4, hd = bh & 15;

  const bf16* Qg = Q + ((size_t)b * 2048 + qt * 128 + qh * 32) * 1024 + hd * 64;
  const bf16* Kg = Kin + (size_t)b * 2048 * 1024 + hd * 64;
  const bf16* Vg = Vt + ((size_t)b * 1024 + hd * 64) * 2048;

  // Q B-fragments: lane holds Q[q = qh*32+q5][k = 16ks+8h+j]
  bf16x8 qf[4];
#pragma unroll
  for (int ks = 0; ks < 4; ++ks)
    qf[ks] = *(const bf16x8*)(Qg + (size_t)q5 * 1024 + ks * 16 + h * 8);

  f32x16 o[2] = {};  // [j]: j=0 -> own d-block (db=kh), j=1 -> partner (db=1-kh)
  float ls = 0.0f;

  // stage both 64-kv tiles of a 128-kv super-tile (512 threads: 1 K + 1 V gload per parity)
  auto stage = [&](int buf, int kv0) {
#pragma unroll
    for (int p = 0; p < 2; ++p) {
      int c = tid;
      int row = c >> 3;
      int sl = (c & 7) ^ (row & 7) ^ ((row >> 3) & 1);  // pre-swizzled global source chunk
      gload_lds16(Kg + (size_t)(kv0 + p * 64 + row) * 1024 + sl * 8, (char*)Ks[buf * 2 + p] + c * 16);
      gload_lds16(Vg + (size_t)row * 2048 + kv0 + p * 64 + sl * 8, (char*)Vs[buf * 2 + p] + c * 16);
    }
  };

  stage(0, 0);
  __syncthreads();
  int cur = 0;

  const int krow = kh * 32 + q5;
  const int kswz = (krow & 7) ^ ((krow >> 3) & 1);

  // two-deep pipeline state (static names — no runtime-indexed arrays)
  unsigned uA[8], uB[8];
  bf16x8 vA[4], vB[4];

  // one 64-kv sub-tile: QK(t) + ldV(t)->vout + PV(t-1) from uin/vin + exp/pack(t)->uout
  auto subtile = [&](int slot4, unsigned (&uin)[8], unsigned (&uout)[8],
                     bf16x8 (&vin)[4], bf16x8 (&vout)[4], bool doPV) {
    // S^T = K_kh * Q_qh^T : 32kv x 32q
    f32x16 s = {};
    __builtin_amdgcn_s_setprio(1);
#pragma unroll
    for (int ks = 0; ks < 4; ++ks) {
      bf16x8 kf = *(const bf16x8*)((const char*)Ks[slot4] + krow * 128 + (((2 * ks + h) ^ kswz) << 4));
      s = __builtin_amdgcn_mfma_f32_32x32x16_bf16(kf, qf[ks], s, 0, 0, 0);
    }

    // V fragments -> registers
#pragma unroll
    for (int j = 0; j < 2; ++j) {
      const int db = kh ^ j;
      const int vrow0 = db * 32 + q5;
      const int vswz = (vrow0 & 7) ^ ((vrow0 >> 3) & 1);
#pragma unroll
      for (int kap = 0; kap < 2; ++kap)
        vout[2 * j + kap] = *(const bf16x8*)((const char*)Vs[slot4] + vrow0 * 128 +
                                             (((4 * kh + 2 * kap + h) ^ vswz) << 4));
    }

    // PV(prev): fully register-fed, fills MFMA pipe while s drains
    if (doPV) {
#pragma unroll
      for (int j = 0; j < 2; ++j)
#pragma unroll
        for (int kap = 0; kap < 2; ++kap) {
          u32x4 uw;
          uw[0] = uin[4 * kap + 0]; uw[1] = uin[4 * kap + 1];
          uw[2] = uin[4 * kap + 2]; uw[3] = uin[4 * kap + 3];
          bf16x8 pa = __builtin_bit_cast(bf16x8, uw);
          o[j] = __builtin_amdgcn_mfma_f32_32x32x16_bf16(pa, vin[2 * j + kap], o[j], 0, 0, 0);
        }
    }
    __builtin_amdgcn_s_setprio(0);

    // P = exp2(S), pack, permlane half-exchange (builtins: hazard-safe)
    float e[16];
#pragma unroll
    for (int jj = 0; jj < 16; ++jj) e[jj] = exp2_b(s[jj]);
    ls += ((((e[0] + e[1]) + (e[2] + e[3])) + ((e[4] + e[5]) + (e[6] + e[7]))) +
           (((e[8] + e[9]) + (e[10] + e[11])) + ((e[12] + e[13]) + (e[14] + e[15]))));
#pragma unroll
    for (int p = 0; p < 8; ++p) uout[p] = cvtpk(e[2 * p], e[2 * p + 1]);
    plswap_b(uout[0], uout[2]); plswap_b(uout[1], uout[3]);
    plswap_b(uout[4], uout[6]); plswap_b(uout[5], uout[7]);
  };

  // 16 fused phases, each covering kv tiles (2k, 2k+1); one barrier per phase
  for (int k = 0; k < 16; ++k) {
    if (k < 15) stage(cur ^ 1, (k + 1) * 128);
    subtile(cur * 2 + 0, uB, uA, vB, vA, k > 0);  // tile 2k:   PV(2k-1)
    subtile(cur * 2 + 1, uA, uB, vA, vB, true);   // tile 2k+1: PV(2k)
    __syncthreads();
    cur ^= 1;
  }
  // final PV(31) from uB/vB (last subtile's outputs)
#pragma unroll
  for (int j = 0; j < 2; ++j)
#pragma unroll
    for (int kap = 0; kap < 2; ++kap) {
      u32x4 uw;
      uw[0] = uB[4 * kap + 0]; uw[1] = uB[4 * kap + 1];
      uw[2] = uB[4 * kap + 2]; uw[3] = uB[4 * kap + 3];
      bf16x8 pa = __builtin_bit_cast(bf16x8, uw);
      o[j] = __builtin_amdgcn_mfma_f32_32x32x16_bf16(pa, vB[2 * j + kap], o[j], 0, 0, 0);
    }

  // ls: cross-h reduce -> every lane holds this wave's 32-kv half-sum for q=q5
  ls += __shfl_xor(ls, 32);

  // cross-wave combine via LDS overlay (Ks/Vs dead after last phase's barrier)
  float* osh = (float*)Ks;  // [8 waves][64 lanes][16] f32 = 32 KB (Ks is 32 KB)
  float* lsf = (float*)Vs;  // [8 waves][32] f32
  *(f32x16*)(osh + ((size_t)(w * 64 + lane)) * 16) = o[1];
  if (h == 0) lsf[w * 32 + q5] = ls;
  __syncthreads();

  const int pw = w ^ 1;  // partner: same q-quarter, other kv-half
  float lt = ls + lsf[pw * 32 + q5];
  float iv = __builtin_amdgcn_rcpf(lt);
  f32x16 p = *(const f32x16*)(osh + ((size_t)(pw * 64 + lane)) * 16);
#pragma unroll
  for (int g4 = 0; g4 < 4; ++g4)
#pragma unroll
    for (int r = 0; r < 4; ++r) {
      int qr = g4 * 8 + 4 * h + r;
      float il = __shfl(iv, qr);
      size_t row = (size_t)b * 2048 + qt * 128 + qh * 32 + qr;
      Oa[row * 1024 + hd * 64 + kh * 32 + q5] = (bf16)((o[0][g4 * 4 + r] + p[g4 * 4 + r]) * il);
    }
}

extern "C" void kernel_launch(void* const* d_in, const int* in_sizes, int n_in,
                              void* d_out, int out_size, void* d_ws, size_t ws_size,
                              hipStream_t stream) {
  (void)in_sizes; (void)n_in; (void)out_size; (void)ws_size;
  const float* x  = (const float*)d_in[0];
  const float* y  = (const float*)d_in[1];
  const float* Wq = (const float*)d_in[2];
  const float* bq = (const float*)d_in[3];
  const float* Wk = (const float*)d_in[4];
  const float* bk = (const float*)d_in[5];
  const float* Wv = (const float*)d_in[6];
  const float* bv = (const float*)d_in[7];
  const float* Wo = (const float*)d_in[8];
  const float* bo = (const float*)d_in[9];

  char* ws = (char*)d_ws;
  bf16* xb  = (bf16*)(ws + 0);
  bf16* yb  = (bf16*)(ws + 8388608);
  bf16* Qb  = (bf16*)(ws + 16777216);
  bf16* Kb  = (bf16*)(ws + 25165824);
  bf16* Vtb = (bf16*)(ws + 33554432);
  bf16* Oab = (bf16*)(ws + 41943040);
  bf16* Wqt = (bf16*)(ws + 50331648);
  bf16* Wkt = (bf16*)(ws + 52428800);
  bf16* Wvt = (bf16*)(ws + 54525952);
  bf16* Wot = (bf16*)(ws + 56623104);

  cvtw_kernel<<<12288, 256, 0, stream>>>(x, y, xb, yb, Wq, Wk, Wv, Wo, Wqt, Wkt, Wvt, Wot);
  gemm_qkv<<<dim3(32, 8, 3), 512, 0, stream>>>(xb, yb, Wqt, Wkt, Wvt, bq, bk, bv, Qb, Kb, Vtb);
  attn_kernel<<<dim3(32, 16), dim3(512), 0, stream>>>(Qb, Kb, Vtb, Oab);
  gemm_out<<<dim3(32, 16), 512, 0, stream>>>(Oab, Wot, bo, (float*)d_out);
}